// Round 6
// baseline (275.558 us; speedup 1.0000x reference)
//
#include <hip/hip_runtime.h>
#include <stdint.h>

// Problem constants
#define L_    8192
#define N_    8
#define L2_   2048
#define K_    16

typedef unsigned int uint;
typedef unsigned short ushort;
typedef unsigned long long u64;

// round-to-nearest-even f32 -> bf16 (monotone)
__device__ __forceinline__ ushort f2b(float f){
  uint u = __float_as_uint(f);
  return (ushort)((u + 0x7FFFu + ((u >> 16) & 1u)) >> 16);
}
// monotone float->uint mapping (handles tiny negative self-distances)
__device__ __forceinline__ uint ford(float f){
  uint u = __float_as_uint(f);
  return u ^ ((uint)((int)u >> 31) | 0x80000000u);
}
// inverse of ford
__device__ __forceinline__ float unford(uint u){
  uint v = (u & 0x80000000u) ? (u ^ 0x80000000u) : ~u;
  return __uint_as_float(v);
}

// ---------------- K0: fused coords prep + keep_coords gather ----------------
// blocks [0,256): cF build; blocks [256,448): keep_coords output
__global__ __launch_bounds__(256) void prep_k(const float* __restrict__ coords,
                                              const int* __restrict__ keep,
                                              float4* __restrict__ cF,
                                              float* __restrict__ out0){
  int b = blockIdx.x;
  if (b < 256){
    int e = b * 256 + threadIdx.x;             // e = l*8+n, e < 65536
    int l = e >> 3, n = e & 7;
    const float* cr = coords + (size_t)e * 3;
    float x = cr[0], y = cr[1], z = cr[2];
    float cc;
    {
      #pragma clang fp contract(off)
      cc = x*x + y*y + z*z;                    // matches np sum(c*c,-1): (xx+yy)+zz
    }
    cF[n * L_ + l] = make_float4(x, y, z, cc);
  } else {
    int t = (b - 256) * 256 + threadIdx.x;     // t < 49152 = L2*N*3
    int i = t / 24; int rem = t - i * 24;      // (n*3+c)
    out0[t] = coords[(size_t)keep[i] * 24 + rem];
  }
}

// ---------------- K1: MLP (2 GEMMs + 2 LayerNorms + ReLU) for rows l<2048 ----------------
__device__ __forceinline__ float wsum(float v){
  #pragma unroll
  for (int o = 32; o; o >>= 1) v += __shfl_down(v, o, 64);
  return v;
}

__global__ __launch_bounds__(128) void mlp_k(const float* __restrict__ feat,
                                             const float* __restrict__ w1,
                                             const float* __restrict__ g1,
                                             const float* __restrict__ b1,
                                             const float* __restrict__ w2,
                                             const float* __restrict__ g2,
                                             const float* __restrict__ b2,
                                             ushort* __restrict__ fB){
  __shared__ float xs[8][64];
  __shared__ float hnl[8][128];
  __shared__ float part[2][2][8];  // [phase][wave][row]
  int tid = threadIdx.x, d = tid, wv = tid >> 6, lane = tid & 63;
  int rg0 = blockIdx.x * 8;

  {
    int r = tid >> 4, k4 = tid & 15;
    int rg = rg0 + r; int l = rg & 2047, n = rg >> 11;
    const float4* src = (const float4*)(feat + (size_t)(l * 8 + n) * 64);
    *(float4*)&xs[r][k4 * 4] = src[k4];
  }
  __syncthreads();

  float acc[8];
  #pragma unroll
  for (int r = 0; r < 8; ++r) acc[r] = 0.f;
  {
    const float4* w1r = (const float4*)(w1 + (size_t)d * 64);
    #pragma unroll
    for (int k4 = 0; k4 < 16; ++k4){
      float4 wq = w1r[k4];
      #pragma unroll
      for (int r = 0; r < 8; ++r){
        float4 xv = *(const float4*)&xs[r][k4 * 4];
        acc[r] += xv.x*wq.x + xv.y*wq.y + xv.z*wq.z + xv.w*wq.w;
      }
    }
  }

  float g1d = g1[d], b1d = b1[d];
  #pragma unroll
  for (int r = 0; r < 8; ++r){ float s = wsum(acc[r]); if (lane == 0) part[0][wv][r] = s; }
  __syncthreads();
  float dv[8];
  #pragma unroll
  for (int r = 0; r < 8; ++r){
    float m = (part[0][0][r] + part[0][1][r]) * 0.0078125f;
    dv[r] = acc[r] - m;
  }
  #pragma unroll
  for (int r = 0; r < 8; ++r){ float s = wsum(dv[r]*dv[r]); if (lane == 0) part[1][wv][r] = s; }
  __syncthreads();
  #pragma unroll
  for (int r = 0; r < 8; ++r){
    float var = (part[1][0][r] + part[1][1][r]) * 0.0078125f;
    float rs = rsqrtf(var + 1e-5f);
    hnl[r][d] = dv[r] * rs * g1d + b1d;
  }
  __syncthreads();

  float a2[8];
  #pragma unroll
  for (int r = 0; r < 8; ++r) a2[r] = 0.f;
  {
    const float4* w2r = (const float4*)(w2 + (size_t)d * 128);
    #pragma unroll 8
    for (int k4 = 0; k4 < 32; ++k4){
      float4 wq = w2r[k4];
      #pragma unroll
      for (int r = 0; r < 8; ++r){
        float4 hv = *(const float4*)&hnl[r][k4 * 4];
        a2[r] += hv.x*wq.x + hv.y*wq.y + hv.z*wq.z + hv.w*wq.w;
      }
    }
  }

  float g2d = g2[d], b2d = b2[d];
  __syncthreads();
  #pragma unroll
  for (int r = 0; r < 8; ++r){ float s = wsum(a2[r]); if (lane == 0) part[0][wv][r] = s; }
  __syncthreads();
  #pragma unroll
  for (int r = 0; r < 8; ++r){
    float m = (part[0][0][r] + part[0][1][r]) * 0.0078125f;
    dv[r] = a2[r] - m;
  }
  #pragma unroll
  for (int r = 0; r < 8; ++r){ float s = wsum(dv[r]*dv[r]); if (lane == 0) part[1][wv][r] = s; }
  __syncthreads();
  #pragma unroll
  for (int r = 0; r < 8; ++r){
    float var = (part[1][0][r] + part[1][1][r]) * 0.0078125f;
    float rs = rsqrtf(var + 1e-5f);
    float o = dv[r] * rs * g2d + b2d;
    o = fmaxf(o, 0.f);
    fB[(size_t)(rg0 + r) * 128 + d] = f2b(o);
  }
}

// ---------------- K2: KNN top-16 (wave-per-query, f32 filter + bitonic drains) ----------------
__device__ __forceinline__ u64 shfl64(u64 v, int src){
  int lo = __shfl((int)(uint)v, src, 64);
  int hi = __shfl((int)(uint)(v >> 32), src, 64);
  return ((u64)(uint)hi << 32) | (uint)lo;
}

// full ascending bitonic sort of 64 u64 keys (one per lane)
__device__ __forceinline__ u64 bsort64(u64 key, int lane){
  #pragma unroll
  for (int k = 2; k <= 64; k <<= 1){
    #pragma unroll
    for (int j = k >> 1; j > 0; j >>= 1){
      u64 o = shfl64(key, lane ^ j);
      bool lower = (lane & j) == 0;
      bool down  = (lane & k) == 0;
      bool takeMin = (lower == down);
      bool oLess = o < key;
      key = (oLess == takeMin) ? o : key;
    }
  }
  return key;
}
// ascending merge of a bitonic 64-sequence
__device__ __forceinline__ u64 bmerge64(u64 key, int lane){
  #pragma unroll
  for (int j = 32; j > 0; j >>= 1){
    u64 o = shfl64(key, lane ^ j);
    bool lower = (lane & j) == 0;
    bool oLess = o < key;
    key = (oLess == lower) ? o : key;
  }
  return key;
}

// exact top-16 of queue (qcount <= 128); tightens hf; resets qcount=16.
// returns per-lane sorted key vector (lane L = L-th smallest).
__device__ __forceinline__ u64 drain(u64* ldsq, int& qcount, float& hf, int lane){
  u64 a = (lane < qcount) ? ldsq[lane] : ~0ull;
  a = bsort64(a, lane);
  if (qcount > 64){
    u64 b = (64 + lane < qcount) ? ldsq[64 + lane] : ~0ull;
    b = bsort64(b, lane);
    u64 br = shfl64(b, 63 - lane);      // concat(A asc, rev(B asc)) is bitonic
    a = a < br ? a : br;
    a = bmerge64(a, lane);
  }
  if (lane < 16) ldsq[lane] = a;
  u64 h = shfl64(a, 15);
  hf = unford((uint)(h >> 32));         // f32 distance of exact 16th-best
  qcount = 16;
  return a;
}

// block = 256 (4 waves); wave = one query g; lane = candidate-in-batch.
// All 4 waves of a block share n and scan the same candidate stream (L1 reuse).
__global__ __launch_bounds__(256) void knn_k(const float4* __restrict__ cF,
                                             const int* __restrict__ keep,
                                             int* __restrict__ nn){
  __shared__ u64 q8[4][128];            // 4 KB: per-wave survivor queue
  int tid = threadIdx.x, lane = tid & 63;
  int wv = tid >> 6;
  int g = blockIdx.x * 4 + wv;          // query id 0..16383
  int n = g >> 11, i = g & 2047;
  u64* ldsq = q8[wv];
  int kidx = keep[i];
  float4 qf = cF[(n << 13) + kidx];     // wave-uniform query {x,y,z,kk}
  const float4* base = cF + (n << 13);

  // ---- seed: sort batch 0 (candidates 0..63) exactly ----
  float hf;
  int qcount;
  {
    float4 cf = base[lane];
    float d2;
    {
      #pragma clang fp contract(off)
      float dot = qf.x*cf.x + qf.y*cf.y + qf.z*cf.z;
      d2 = (qf.w + cf.w) - 2.0f * dot;
    }
    u64 key = ((u64)ford(d2) << 32) | (uint)lane;
    key = bsort64(key, lane);
    if (lane < 16) ldsq[lane] = key;
    u64 h = shfl64(key, 15);
    hf = unford((uint)(h >> 32));
    qcount = 16;
  }

  // ---- main scan: batches 1..127, cheap f32 filter ----
  for (int b = 1; b < 128; ++b){
    int j = (b << 6) + lane;
    float4 cf = base[j];                // coalesced dwordx4; shared stream in block
    float d2;
    {
      #pragma clang fp contract(off)
      float dot = qf.x*cf.x + qf.y*cf.y + qf.z*cf.z;
      d2 = (qf.w + cf.w) - 2.0f * dot;
    }
    bool pred = d2 <= hf;               // ties admitted; drain is exact on (d2,idx)
    u64 bal = __ballot(pred);
    if (bal){
      if (pred){
        u64 key = ((u64)ford(d2) << 32) | (uint)j;
        int rel = __builtin_amdgcn_mbcnt_lo((uint)bal, 0);
        rel = __builtin_amdgcn_mbcnt_hi((uint)(bal >> 32), rel);
        ldsq[qcount + rel] = key;
      }
      qcount += __popcll(bal);
      if (qcount >= 65) drain(ldsq, qcount, hf, lane);  // cap: 64 + 64 <= 128
    }
  }
  u64 a = drain(ldsq, qcount, hf, lane);
  if (lane < 16)
    nn[g * 16 + lane] = (int)(a & 2047u);   // fmod(L2) quirk
}

// ---------------- K3: gather + max-pool (f32 output) ----------------
__global__ __launch_bounds__(256) void pool_k(const int* __restrict__ nn,
                                              const uint* __restrict__ fB32,
                                              float* __restrict__ out1){
  int tid = threadIdx.x; int lane = tid & 63;
  int qq = __builtin_amdgcn_readfirstlane(blockIdx.x * 4 + (tid >> 6)); // n*2048+i
  int n = qq >> 11, i = qq & 2047;
  const int* nnq = nn + qq * 16;
  float m0 = -3.4e38f, m1 = -3.4e38f;
  #pragma unroll
  for (int k = 0; k < 16; ++k){
    int l = nnq[k];
    uint u = fB32[(size_t)((n << 11) + l) * 64 + lane];
    float f0 = __uint_as_float((u & 0xFFFFu) << 16);
    float f1 = __uint_as_float((u >> 16) << 16);
    m0 = fmaxf(m0, f0); m1 = fmaxf(m1, f1);
  }
  float2* o2 = (float2*)(out1 + (size_t)(i * 8 + n) * 128);
  o2[lane] = make_float2(m0, m1);
}

extern "C" void kernel_launch(void* const* d_in, const int* in_sizes, int n_in,
                              void* d_out, int out_size, void* d_ws, size_t ws_size,
                              hipStream_t stream){
  const float* coords = (const float*)d_in[0];
  const float* feat   = (const float*)d_in[1];
  const float* w1     = (const float*)d_in[2];
  const float* g1     = (const float*)d_in[3];
  const float* b1     = (const float*)d_in[4];
  const float* w2     = (const float*)d_in[5];
  const float* g2     = (const float*)d_in[6];
  const float* b2     = (const float*)d_in[7];
  const int*   keep   = (const int*)d_in[8];
  float* out0 = (float*)d_out;                    // keep_coords [2048,8,3]
  float* out1 = out0 + 49152;                     // pool_features [2048,8,128]

  char* ws = (char*)d_ws;
  float4* cF = (float4*)ws;                       // [N][L] f32x4 : 1 MB
  ushort* fB = (ushort*)(ws + (1 << 20));         // [N][L2][128] bf16 : 4 MB
  int*    nn = (int*)(ws + (5 << 20));            // [N][L2][16] i32 : 1 MB

  hipLaunchKernelGGL(prep_k,  dim3(448),  dim3(256), 0, stream, coords, keep, cF, out0);
  hipLaunchKernelGGL(mlp_k,   dim3(2048), dim3(128), 0, stream,
                     feat, w1, g1, b1, w2, g2, b2, fB);
  hipLaunchKernelGGL(knn_k,   dim3(4096), dim3(256), 0, stream, cF, keep, nn);
  hipLaunchKernelGGL(pool_k,  dim3(4096), dim3(256), 0, stream, nn, (const uint*)fB, out1);
}

// Round 7
// 249.617 us; speedup vs baseline: 1.1039x; 1.1039x over previous
//
#include <hip/hip_runtime.h>
#include <stdint.h>

// Problem constants
#define L_    8192
#define N_    8
#define L2_   2048
#define K_    16

typedef unsigned int uint;
typedef unsigned short ushort;
typedef unsigned long long u64;

// round-to-nearest-even f32 -> bf16 (monotone)
__device__ __forceinline__ ushort f2b(float f){
  uint u = __float_as_uint(f);
  return (ushort)((u + 0x7FFFu + ((u >> 16) & 1u)) >> 16);
}
// monotone float->uint mapping (handles tiny negative self-distances)
__device__ __forceinline__ uint ford(float f){
  uint u = __float_as_uint(f);
  return u ^ ((uint)((int)u >> 31) | 0x80000000u);
}
// inverse of ford
__device__ __forceinline__ float unford(uint u){
  uint v = (u & 0x80000000u) ? (u ^ 0x80000000u) : ~u;
  return __uint_as_float(v);
}

// ---------------- K0: fused coords prep + keep_coords gather ----------------
__global__ __launch_bounds__(256) void prep_k(const float* __restrict__ coords,
                                              const int* __restrict__ keep,
                                              float4* __restrict__ cF,
                                              float* __restrict__ out0){
  int b = blockIdx.x;
  if (b < 256){
    int e = b * 256 + threadIdx.x;             // e = l*8+n, e < 65536
    int l = e >> 3, n = e & 7;
    const float* cr = coords + (size_t)e * 3;
    float x = cr[0], y = cr[1], z = cr[2];
    float cc;
    {
      #pragma clang fp contract(off)
      cc = x*x + y*y + z*z;                    // matches np sum(c*c,-1): (xx+yy)+zz
    }
    cF[n * L_ + l] = make_float4(x, y, z, cc);
  } else {
    int t = (b - 256) * 256 + threadIdx.x;     // t < 49152 = L2*N*3
    int i = t / 24; int rem = t - i * 24;      // (n*3+c)
    out0[t] = coords[(size_t)keep[i] * 24 + rem];
  }
}

// ---------------- K1: MLP (2 GEMMs + 2 LayerNorms + ReLU) for rows l<2048 ----------------
__device__ __forceinline__ float wsum(float v){
  #pragma unroll
  for (int o = 32; o; o >>= 1) v += __shfl_down(v, o, 64);
  return v;
}

__global__ __launch_bounds__(128) void mlp_k(const float* __restrict__ feat,
                                             const float* __restrict__ w1,
                                             const float* __restrict__ g1,
                                             const float* __restrict__ b1,
                                             const float* __restrict__ w2,
                                             const float* __restrict__ g2,
                                             const float* __restrict__ b2,
                                             ushort* __restrict__ fB){
  __shared__ float xs[8][64];
  __shared__ float hnl[8][128];
  __shared__ float part[2][2][8];  // [phase][wave][row]
  int tid = threadIdx.x, d = tid, wv = tid >> 6, lane = tid & 63;
  int rg0 = blockIdx.x * 8;

  {
    int r = tid >> 4, k4 = tid & 15;
    int rg = rg0 + r; int l = rg & 2047, n = rg >> 11;
    const float4* src = (const float4*)(feat + (size_t)(l * 8 + n) * 64);
    *(float4*)&xs[r][k4 * 4] = src[k4];
  }
  __syncthreads();

  float acc[8];
  #pragma unroll
  for (int r = 0; r < 8; ++r) acc[r] = 0.f;
  {
    const float4* w1r = (const float4*)(w1 + (size_t)d * 64);
    #pragma unroll
    for (int k4 = 0; k4 < 16; ++k4){
      float4 wq = w1r[k4];
      #pragma unroll
      for (int r = 0; r < 8; ++r){
        float4 xv = *(const float4*)&xs[r][k4 * 4];
        acc[r] += xv.x*wq.x + xv.y*wq.y + xv.z*wq.z + xv.w*wq.w;
      }
    }
  }

  float g1d = g1[d], b1d = b1[d];
  #pragma unroll
  for (int r = 0; r < 8; ++r){ float s = wsum(acc[r]); if (lane == 0) part[0][wv][r] = s; }
  __syncthreads();
  float dv[8];
  #pragma unroll
  for (int r = 0; r < 8; ++r){
    float m = (part[0][0][r] + part[0][1][r]) * 0.0078125f;
    dv[r] = acc[r] - m;
  }
  #pragma unroll
  for (int r = 0; r < 8; ++r){ float s = wsum(dv[r]*dv[r]); if (lane == 0) part[1][wv][r] = s; }
  __syncthreads();
  #pragma unroll
  for (int r = 0; r < 8; ++r){
    float var = (part[1][0][r] + part[1][1][r]) * 0.0078125f;
    float rs = rsqrtf(var + 1e-5f);
    hnl[r][d] = dv[r] * rs * g1d + b1d;
  }
  __syncthreads();

  float a2[8];
  #pragma unroll
  for (int r = 0; r < 8; ++r) a2[r] = 0.f;
  {
    const float4* w2r = (const float4*)(w2 + (size_t)d * 128);
    #pragma unroll 8
    for (int k4 = 0; k4 < 32; ++k4){
      float4 wq = w2r[k4];
      #pragma unroll
      for (int r = 0; r < 8; ++r){
        float4 hv = *(const float4*)&hnl[r][k4 * 4];
        a2[r] += hv.x*wq.x + hv.y*wq.y + hv.z*wq.z + hv.w*wq.w;
      }
    }
  }

  float g2d = g2[d], b2d = b2[d];
  __syncthreads();
  #pragma unroll
  for (int r = 0; r < 8; ++r){ float s = wsum(a2[r]); if (lane == 0) part[0][wv][r] = s; }
  __syncthreads();
  #pragma unroll
  for (int r = 0; r < 8; ++r){
    float m = (part[0][0][r] + part[0][1][r]) * 0.0078125f;
    dv[r] = a2[r] - m;
  }
  #pragma unroll
  for (int r = 0; r < 8; ++r){ float s = wsum(dv[r]*dv[r]); if (lane == 0) part[1][wv][r] = s; }
  __syncthreads();
  #pragma unroll
  for (int r = 0; r < 8; ++r){
    float var = (part[1][0][r] + part[1][1][r]) * 0.0078125f;
    float rs = rsqrtf(var + 1e-5f);
    float o = dv[r] * rs * g2d + b2d;
    o = fmaxf(o, 0.f);
    fB[(size_t)(rg0 + r) * 128 + d] = f2b(o);
  }
}

// ---------------- K2: fused KNN top-16 + gather/max-pool ----------------
__device__ __forceinline__ u64 shfl64(u64 v, int src){
  int lo = __shfl((int)(uint)v, src, 64);
  int hi = __shfl((int)(uint)(v >> 32), src, 64);
  return ((u64)(uint)hi << 32) | (uint)lo;
}

// full ascending bitonic sort of 64 u64 keys (one per lane)
__device__ __forceinline__ u64 bsort64(u64 key, int lane){
  #pragma unroll
  for (int k = 2; k <= 64; k <<= 1){
    #pragma unroll
    for (int j = k >> 1; j > 0; j >>= 1){
      u64 o = shfl64(key, lane ^ j);
      bool lower = (lane & j) == 0;
      bool down  = (lane & k) == 0;
      bool takeMin = (lower == down);
      bool oLess = o < key;
      key = (oLess == takeMin) ? o : key;
    }
  }
  return key;
}
// ascending merge of a bitonic 64-sequence
__device__ __forceinline__ u64 bmerge64(u64 key, int lane){
  #pragma unroll
  for (int j = 32; j > 0; j >>= 1){
    u64 o = shfl64(key, lane ^ j);
    bool lower = (lane & j) == 0;
    bool oLess = o < key;
    key = (oLess == lower) ? o : key;
  }
  return key;
}

// exact top-16 of queue (qcount <= 128); tightens hf; resets qcount=16.
__device__ __forceinline__ u64 drain(u64* ldsq, int& qcount, float& hf, int lane){
  u64 a = (lane < qcount) ? ldsq[lane] : ~0ull;
  a = bsort64(a, lane);
  if (qcount > 64){
    u64 b = (64 + lane < qcount) ? ldsq[64 + lane] : ~0ull;
    b = bsort64(b, lane);
    u64 br = shfl64(b, 63 - lane);      // concat(A asc, rev(B asc)) is bitonic
    a = a < br ? a : br;
    a = bmerge64(a, lane);
  }
  if (lane < 16) ldsq[lane] = a;
  u64 h = shfl64(a, 15);
  hf = unford((uint)(h >> 32));         // f32 distance of exact 16th-best
  qcount = 16;
  return a;
}

// block = 256 (4 waves); wave = one query g; lane = candidate-in-batch.
// All 4 waves share batch n -> candidate stream reuse in L1/L2.
__global__ __launch_bounds__(256) void knn_pool_k(const float4* __restrict__ cF,
                                                  const int* __restrict__ keep,
                                                  const uint* __restrict__ fB32,
                                                  float* __restrict__ out1){
  __shared__ u64 q8[4][128];            // 4 KB: per-wave survivor queue
  int tid = threadIdx.x, lane = tid & 63;
  int wv = tid >> 6;
  int g = blockIdx.x * 4 + wv;          // query id 0..16383
  int n = g >> 11, i = g & 2047;
  u64* ldsq = q8[wv];
  int kidx = keep[i];
  float4 qf = cF[(n << 13) + kidx];     // wave-uniform query {x,y,z,kk}
  const float4* base = cF + (n << 13);

  float hf;
  int qcount;

  // d2 for one candidate (bit-exact np association)
  #define D2(cf, out) { \
    _Pragma("clang fp contract(off)") \
    float dot = qf.x*(cf).x + qf.y*(cf).y + qf.z*(cf).z; \
    out = (qf.w + (cf).w) - 2.0f * dot; \
  }
  // filter + ballot-compact + conditional drain for one 64-candidate batch
  #define PROC(cf, jidx) { \
    float d2; D2(cf, d2); \
    bool pred = d2 <= hf; \
    u64 bal = __ballot(pred); \
    if (bal){ \
      if (pred){ \
        u64 key = ((u64)ford(d2) << 32) | (uint)(jidx); \
        int rel = __builtin_amdgcn_mbcnt_lo((uint)bal, 0); \
        rel = __builtin_amdgcn_mbcnt_hi((uint)(bal >> 32), rel); \
        ldsq[qcount + rel] = key; \
      } \
      qcount += __popcll(bal); \
      if (qcount >= 65) drain(ldsq, qcount, hf, lane); \
    } \
  }

  // ---- seed: exact sort of batch 0 ----
  {
    float4 cf = base[lane];
    float d2; D2(cf, d2);
    u64 key = ((u64)ford(d2) << 32) | (uint)lane;
    key = bsort64(key, lane);
    if (lane < 16) ldsq[lane] = key;
    u64 h = shfl64(key, 15);
    hf = unford((uint)(h >> 32));
    qcount = 16;
  }

  // ---- head: batches 1..3 ----
  for (int b = 1; b < 4; ++b){
    float4 cf = base[(b << 6) + lane];
    PROC(cf, (b << 6) + lane);
  }

  // ---- main: batches 4..127, 4-wide software pipeline (4 loads in flight) ----
  for (int b = 4; b < 128; b += 4){
    const float4* p = base + (b << 6) + lane;
    float4 c0 = p[0];
    float4 c1 = p[64];
    float4 c2 = p[128];
    float4 c3 = p[192];
    int j0 = (b << 6) + lane;
    PROC(c0, j0);
    PROC(c1, j0 + 64);
    PROC(c2, j0 + 128);
    PROC(c3, j0 + 192);
  }
  u64 a = drain(ldsq, qcount, hf, lane);
  #undef PROC
  #undef D2

  // ---- fused pool: top-16 idx held in lanes 0..15 of a ----
  const uint* frow = fB32 + ((size_t)(n << 11) << 6);   // fB[n][0][:]
  float m0 = -3.4e38f, m1 = -3.4e38f;
  #pragma unroll
  for (int k = 0; k < 16; ++k){
    int idx = (int)(shfl64(a, k) & 2047u);              // fmod(L2) quirk
    uint u = frow[((size_t)idx << 6) + lane];           // coalesced 256B row
    float f0 = __uint_as_float((u & 0xFFFFu) << 16);
    float f1 = __uint_as_float((u >> 16) << 16);
    m0 = fmaxf(m0, f0); m1 = fmaxf(m1, f1);
  }
  float2* o2 = (float2*)(out1 + (size_t)(i * 8 + n) * 128);
  o2[lane] = make_float2(m0, m1);
}

extern "C" void kernel_launch(void* const* d_in, const int* in_sizes, int n_in,
                              void* d_out, int out_size, void* d_ws, size_t ws_size,
                              hipStream_t stream){
  const float* coords = (const float*)d_in[0];
  const float* feat   = (const float*)d_in[1];
  const float* w1     = (const float*)d_in[2];
  const float* g1     = (const float*)d_in[3];
  const float* b1     = (const float*)d_in[4];
  const float* w2     = (const float*)d_in[5];
  const float* g2     = (const float*)d_in[6];
  const float* b2     = (const float*)d_in[7];
  const int*   keep   = (const int*)d_in[8];
  float* out0 = (float*)d_out;                    // keep_coords [2048,8,3]
  float* out1 = out0 + 49152;                     // pool_features [2048,8,128]

  char* ws = (char*)d_ws;
  float4* cF = (float4*)ws;                       // [N][L] f32x4 : 1 MB
  ushort* fB = (ushort*)(ws + (1 << 20));         // [N][L2][128] bf16 : 4 MB

  hipLaunchKernelGGL(prep_k,      dim3(448),  dim3(256), 0, stream, coords, keep, cF, out0);
  hipLaunchKernelGGL(mlp_k,       dim3(2048), dim3(128), 0, stream,
                     feat, w1, g1, b1, w2, g2, b2, fB);
  hipLaunchKernelGGL(knn_pool_k,  dim3(4096), dim3(256), 0, stream,
                     cF, keep, (const uint*)fB, out1);
}

// Round 8
// 234.325 us; speedup vs baseline: 1.1760x; 1.0653x over previous
//
#include <hip/hip_runtime.h>
#include <stdint.h>

// Problem constants
#define L_    8192
#define N_    8
#define L2_   2048
#define K_    16

typedef unsigned int uint;
typedef unsigned short ushort;
typedef unsigned long long u64;

// round-to-nearest-even f32 -> bf16 (monotone)
__device__ __forceinline__ ushort f2b(float f){
  uint u = __float_as_uint(f);
  return (ushort)((u + 0x7FFFu + ((u >> 16) & 1u)) >> 16);
}
// monotone float->uint mapping (handles tiny negative self-distances)
__device__ __forceinline__ uint ford(float f){
  uint u = __float_as_uint(f);
  return u ^ ((uint)((int)u >> 31) | 0x80000000u);
}
// inverse of ford
__device__ __forceinline__ float unford(uint u){
  uint v = (u & 0x80000000u) ? (u ^ 0x80000000u) : ~u;
  return __uint_as_float(v);
}

// ---------------- K1: MLP + (fused) coords prep + keep_coords ----------------
// blocks [0,2048): MLP, 8 rows each (128 thr = one per out dim)
// blocks [2048,2560): cF build (128 elems each)
// blocks [2560,2944): keep_coords gather (128 elems each)
__device__ __forceinline__ float wsum(float v){
  #pragma unroll
  for (int o = 32; o; o >>= 1) v += __shfl_down(v, o, 64);
  return v;
}

__global__ __launch_bounds__(128) void mlp_prep_k(const float* __restrict__ feat,
                                                  const float* __restrict__ w1,
                                                  const float* __restrict__ g1,
                                                  const float* __restrict__ b1,
                                                  const float* __restrict__ w2,
                                                  const float* __restrict__ g2,
                                                  const float* __restrict__ b2,
                                                  ushort* __restrict__ fB,
                                                  const float* __restrict__ coords,
                                                  const int* __restrict__ keep,
                                                  float4* __restrict__ cF,
                                                  float* __restrict__ out0){
  int blk = blockIdx.x;
  if (blk >= 2048){
    int tid = threadIdx.x;
    if (blk < 2560){
      int e = (blk - 2048) * 128 + tid;        // e = l*8+n, e < 65536
      int l = e >> 3, n = e & 7;
      const float* cr = coords + (size_t)e * 3;
      float x = cr[0], y = cr[1], z = cr[2];
      float cc;
      {
        #pragma clang fp contract(off)
        cc = x*x + y*y + z*z;                  // matches np sum(c*c,-1): (xx+yy)+zz
      }
      cF[n * L_ + l] = make_float4(x, y, z, cc);
    } else {
      int t = (blk - 2560) * 128 + tid;        // t < 49152 = L2*N*3
      int i = t / 24; int rem = t - i * 24;    // (n*3+c)
      out0[t] = coords[(size_t)keep[i] * 24 + rem];
    }
    return;
  }

  __shared__ float xs[8][64];
  __shared__ float hnl[8][128];
  __shared__ float part[2][2][8];  // [phase][wave][row]
  int tid = threadIdx.x, d = tid, wv = tid >> 6, lane = tid & 63;
  int rg0 = blk * 8;

  {
    int r = tid >> 4, k4 = tid & 15;
    int rg = rg0 + r; int l = rg & 2047, n = rg >> 11;
    const float4* src = (const float4*)(feat + (size_t)(l * 8 + n) * 64);
    *(float4*)&xs[r][k4 * 4] = src[k4];
  }
  __syncthreads();

  float acc[8];
  #pragma unroll
  for (int r = 0; r < 8; ++r) acc[r] = 0.f;
  {
    const float4* w1r = (const float4*)(w1 + (size_t)d * 64);
    #pragma unroll
    for (int k4 = 0; k4 < 16; ++k4){
      float4 wq = w1r[k4];
      #pragma unroll
      for (int r = 0; r < 8; ++r){
        float4 xv = *(const float4*)&xs[r][k4 * 4];
        acc[r] += xv.x*wq.x + xv.y*wq.y + xv.z*wq.z + xv.w*wq.w;
      }
    }
  }

  float g1d = g1[d], b1d = b1[d];
  #pragma unroll
  for (int r = 0; r < 8; ++r){ float s = wsum(acc[r]); if (lane == 0) part[0][wv][r] = s; }
  __syncthreads();
  float dv[8];
  #pragma unroll
  for (int r = 0; r < 8; ++r){
    float m = (part[0][0][r] + part[0][1][r]) * 0.0078125f;
    dv[r] = acc[r] - m;
  }
  #pragma unroll
  for (int r = 0; r < 8; ++r){ float s = wsum(dv[r]*dv[r]); if (lane == 0) part[1][wv][r] = s; }
  __syncthreads();
  #pragma unroll
  for (int r = 0; r < 8; ++r){
    float var = (part[1][0][r] + part[1][1][r]) * 0.0078125f;
    float rs = rsqrtf(var + 1e-5f);
    hnl[r][d] = dv[r] * rs * g1d + b1d;
  }
  __syncthreads();

  float a2[8];
  #pragma unroll
  for (int r = 0; r < 8; ++r) a2[r] = 0.f;
  {
    const float4* w2r = (const float4*)(w2 + (size_t)d * 128);
    #pragma unroll 8
    for (int k4 = 0; k4 < 32; ++k4){
      float4 wq = w2r[k4];
      #pragma unroll
      for (int r = 0; r < 8; ++r){
        float4 hv = *(const float4*)&hnl[r][k4 * 4];
        a2[r] += hv.x*wq.x + hv.y*wq.y + hv.z*wq.z + hv.w*wq.w;
      }
    }
  }

  float g2d = g2[d], b2d = b2[d];
  __syncthreads();
  #pragma unroll
  for (int r = 0; r < 8; ++r){ float s = wsum(a2[r]); if (lane == 0) part[0][wv][r] = s; }
  __syncthreads();
  #pragma unroll
  for (int r = 0; r < 8; ++r){
    float m = (part[0][0][r] + part[0][1][r]) * 0.0078125f;
    dv[r] = a2[r] - m;
  }
  #pragma unroll
  for (int r = 0; r < 8; ++r){ float s = wsum(dv[r]*dv[r]); if (lane == 0) part[1][wv][r] = s; }
  __syncthreads();
  #pragma unroll
  for (int r = 0; r < 8; ++r){
    float var = (part[1][0][r] + part[1][1][r]) * 0.0078125f;
    float rs = rsqrtf(var + 1e-5f);
    float o = dv[r] * rs * g2d + b2d;
    o = fmaxf(o, 0.f);
    fB[(size_t)(rg0 + r) * 128 + d] = f2b(o);
  }
}

// ---------------- K2: fused KNN top-16 + gather/max-pool ----------------
__device__ __forceinline__ u64 shfl64(u64 v, int src){
  int lo = __shfl((int)(uint)v, src, 64);
  int hi = __shfl((int)(uint)(v >> 32), src, 64);
  return ((u64)(uint)hi << 32) | (uint)lo;
}

// full ascending bitonic sort of 64 u64 keys (one per lane)
__device__ __forceinline__ u64 bsort64(u64 key, int lane){
  #pragma unroll
  for (int k = 2; k <= 64; k <<= 1){
    #pragma unroll
    for (int j = k >> 1; j > 0; j >>= 1){
      u64 o = shfl64(key, lane ^ j);
      bool lower = (lane & j) == 0;
      bool down  = (lane & k) == 0;
      bool takeMin = (lower == down);
      bool oLess = o < key;
      key = (oLess == takeMin) ? o : key;
    }
  }
  return key;
}
// ascending merge of a bitonic 64-sequence
__device__ __forceinline__ u64 bmerge64(u64 key, int lane){
  #pragma unroll
  for (int j = 32; j > 0; j >>= 1){
    u64 o = shfl64(key, lane ^ j);
    bool lower = (lane & j) == 0;
    bool oLess = o < key;
    key = (oLess == lower) ? o : key;
  }
  return key;
}

// exact top-16 of queue (qcount <= 112); tightens hf; resets qcount=16.
// trigger at 49 keeps the common case on the single-sort path.
__device__ __forceinline__ u64 drain(u64* ldsq, int& qcount, float& hf, int lane){
  u64 a = (lane < qcount) ? ldsq[lane] : ~0ull;
  a = bsort64(a, lane);
  if (qcount > 64){
    u64 b = (64 + lane < qcount) ? ldsq[64 + lane] : ~0ull;
    b = bsort64(b, lane);
    u64 br = shfl64(b, 63 - lane);      // concat(A asc, rev(B asc)) is bitonic
    a = a < br ? a : br;
    a = bmerge64(a, lane);
  }
  if (lane < 16) ldsq[lane] = a;
  u64 h = shfl64(a, 15);
  hf = unford((uint)(h >> 32));         // exact f32 distance of 16th-best
  qcount = 16;
  return a;
}

// block = 256 (4 waves); wave = one query g; lane = candidate-in-batch.
__global__ __launch_bounds__(256) void knn_pool_k(const float4* __restrict__ cF,
                                                  const int* __restrict__ keep,
                                                  const uint* __restrict__ fB32,
                                                  float* __restrict__ out1){
  __shared__ u64 q8[4][128];            // 4 KB: per-wave survivor queue
  int tid = threadIdx.x, lane = tid & 63;
  int wv = tid >> 6;
  int g = blockIdx.x * 4 + wv;          // query id 0..16383
  int n = g >> 11, i = g & 2047;
  u64* ldsq = q8[wv];
  int kidx = keep[i];
  float4 qf = cF[(n << 13) + kidx];     // wave-uniform query {x,y,z,kk}
  const float4* base = cF + (n << 13);

  float hf  = 3.4e38f;                  // exact threshold (16th-best so far)
  float hfr = 3.4e38f;                  // relaxed: hf + margin >> fma-contraction err
  int qcount = 0;

  // fast FMA filter (superset of exact test via margin); exact d2 only for survivors
  #define PROC(cf, jidx) { \
    float dotf = __builtin_fmaf(qf.x,(cf).x, __builtin_fmaf(qf.y,(cf).y, qf.z*(cf).z)); \
    float d2f  = __builtin_fmaf(-2.0f, dotf, qf.w + (cf).w); \
    bool pred = d2f <= hfr; \
    u64 bal = __ballot(pred); \
    if (bal){ \
      if (pred){ \
        float d2; \
        { \
          _Pragma("clang fp contract(off)") \
          float dot = qf.x*(cf).x + qf.y*(cf).y + qf.z*(cf).z; \
          d2 = (qf.w + (cf).w) - 2.0f * dot; \
        } \
        u64 key = ((u64)ford(d2) << 32) | (uint)(jidx); \
        int rel = __builtin_amdgcn_mbcnt_lo((uint)bal, 0); \
        rel = __builtin_amdgcn_mbcnt_hi((uint)(bal >> 32), rel); \
        ldsq[qcount + rel] = key; \
      } \
      qcount += __popcll(bal); \
      if (qcount >= 49){ drain(ldsq, qcount, hf, lane); hfr = hf + 1e-3f; } \
    } \
  }

  // main scan: 4-wide software pipeline; batch 0 floods (h=inf) -> immediate
  // single-sort drain = implicit exact seed.
  for (int b = 0; b < 128; b += 4){
    const float4* p = base + (b << 6) + lane;
    float4 c0 = p[0];
    float4 c1 = p[64];
    float4 c2 = p[128];
    float4 c3 = p[192];
    int j0 = (b << 6) + lane;
    PROC(c0, j0);
    PROC(c1, j0 + 64);
    PROC(c2, j0 + 128);
    PROC(c3, j0 + 192);
  }
  u64 a = drain(ldsq, qcount, hf, lane);
  #undef PROC

  // fused pool: sorted top-16 keys live in lanes 0..15 of a
  const uint* frow = fB32 + ((size_t)(n << 11) << 6);   // fB[n][0][:]
  float m0 = -3.4e38f, m1 = -3.4e38f;
  #pragma unroll
  for (int k = 0; k < 16; ++k){
    int idx = (int)(shfl64(a, k) & 2047u);              // fmod(L2) quirk
    uint u = frow[((size_t)idx << 6) + lane];           // coalesced 256B row
    float f0 = __uint_as_float((u & 0xFFFFu) << 16);
    float f1 = __uint_as_float((u >> 16) << 16);
    m0 = fmaxf(m0, f0); m1 = fmaxf(m1, f1);
  }
  float2* o2 = (float2*)(out1 + (size_t)(i * 8 + n) * 128);
  o2[lane] = make_float2(m0, m1);
}

extern "C" void kernel_launch(void* const* d_in, const int* in_sizes, int n_in,
                              void* d_out, int out_size, void* d_ws, size_t ws_size,
                              hipStream_t stream){
  const float* coords = (const float*)d_in[0];
  const float* feat   = (const float*)d_in[1];
  const float* w1     = (const float*)d_in[2];
  const float* g1     = (const float*)d_in[3];
  const float* b1     = (const float*)d_in[4];
  const float* w2     = (const float*)d_in[5];
  const float* g2     = (const float*)d_in[6];
  const float* b2     = (const float*)d_in[7];
  const int*   keep   = (const int*)d_in[8];
  float* out0 = (float*)d_out;                    // keep_coords [2048,8,3]
  float* out1 = out0 + 49152;                     // pool_features [2048,8,128]

  char* ws = (char*)d_ws;
  float4* cF = (float4*)ws;                       // [N][L] f32x4 : 1 MB
  ushort* fB = (ushort*)(ws + (1 << 20));         // [N][L2][128] bf16 : 4 MB

  hipLaunchKernelGGL(mlp_prep_k, dim3(2944), dim3(128), 0, stream,
                     feat, w1, g1, b1, w2, g2, b2, fB, coords, keep, cF, out0);
  hipLaunchKernelGGL(knn_pool_k, dim3(4096), dim3(256), 0, stream,
                     cF, keep, (const uint*)fB, out1);
}

// Round 9
// 204.033 us; speedup vs baseline: 1.3506x; 1.1485x over previous
//
#include <hip/hip_runtime.h>
#include <stdint.h>

// Problem constants
#define L_    8192
#define N_    8
#define L2_   2048
#define K_    16

typedef unsigned int uint;
typedef unsigned short ushort;
typedef unsigned long long u64;

// round-to-nearest-even f32 -> bf16 (monotone)
__device__ __forceinline__ ushort f2b(float f){
  uint u = __float_as_uint(f);
  return (ushort)((u + 0x7FFFu + ((u >> 16) & 1u)) >> 16);
}
// monotone float->uint mapping (handles tiny negative self-distances)
__device__ __forceinline__ uint ford(float f){
  uint u = __float_as_uint(f);
  return u ^ ((uint)((int)u >> 31) | 0x80000000u);
}
// inverse of ford
__device__ __forceinline__ float unford(uint u){
  uint v = (u & 0x80000000u) ? (u ^ 0x80000000u) : ~u;
  return __uint_as_float(v);
}

// ---------------- K1: MLP (scalar-weight GEMM) + coords prep + keep_coords ----------------
// blocks [0,256): MLP, 64 rows each; block = 512 thr = 8 waves; lane = row,
//   wave wv owns output dims [16*wv, 16*wv+16) (wave-uniform -> weights via s_load).
// blocks [256,384): cF build. blocks [384,480): keep_coords gather.
__global__ __launch_bounds__(512) void mlp_prep_k(const float* __restrict__ feat,
                                                  const float* __restrict__ w1,
                                                  const float* __restrict__ g1,
                                                  const float* __restrict__ b1,
                                                  const float* __restrict__ w2,
                                                  const float* __restrict__ g2,
                                                  const float* __restrict__ b2,
                                                  uint* __restrict__ fBw,
                                                  const float* __restrict__ coords,
                                                  const int* __restrict__ keep,
                                                  float4* __restrict__ cF,
                                                  float* __restrict__ out0){
  int blk = blockIdx.x;
  int tid = threadIdx.x;
  if (blk >= 256){
    if (blk < 384){
      int e = (blk - 256) * 512 + tid;         // e = l*8+n, e < 65536
      int l = e >> 3, n = e & 7;
      const float* cr = coords + (size_t)e * 3;
      float x = cr[0], y = cr[1], z = cr[2];
      float cc;
      {
        #pragma clang fp contract(off)
        cc = x*x + y*y + z*z;                  // matches np sum(c*c,-1): (xx+yy)+zz
      }
      cF[n * L_ + l] = make_float4(x, y, z, cc);
    } else {
      int t = (blk - 384) * 512 + tid;         // t < 49152 = L2*N*3
      int i = t / 24; int rem = t - i * 24;    // (n*3+c)
      out0[t] = coords[(size_t)keep[i] * 24 + rem];
    }
    return;
  }

  __shared__ float xs[64][68];    // x rows   (pad 68: 16B-aligned, even bank segs)
  __shared__ float hn[64][132];   // LN1 rows (pad 132)
  __shared__ float part[8][64];   // LN partial sums [wave][row]
  int lane = tid & 63;
  int wv = __builtin_amdgcn_readfirstlane(tid >> 6);
  int nbase = wv * 16;
  int rg0 = blk * 64;

  // ---- stage x: 64 rows x 64 f32; thread t -> row t>>3, cols (t&7)*8..+7 ----
  {
    int row = tid >> 3, k0 = (tid & 7) * 8;
    int rg = rg0 + row; int l = rg & 2047, nb = rg >> 11;
    const float4* src = (const float4*)(feat + (size_t)((l << 3) + nb) * 64 + k0);
    float4 a0 = src[0], a1 = src[1];
    *(float4*)&xs[row][k0]     = a0;
    *(float4*)&xs[row][k0 + 4] = a1;
  }
  __syncthreads();

  // ---- GEMM1: acc[d] = x[lane] . w1[nbase+d], weights via scalar loads ----
  float acc[16];
  #pragma unroll
  for (int d = 0; d < 16; ++d) acc[d] = 0.f;
  #pragma unroll 2
  for (int k4 = 0; k4 < 16; ++k4){
    float4 xv = *(const float4*)&xs[lane][k4 * 4];
    #pragma unroll
    for (int d = 0; d < 16; ++d){
      float4 wq = ((const float4*)(w1 + (size_t)(nbase + d) * 64))[k4];
      acc[d] += xv.x*wq.x + xv.y*wq.y + xv.z*wq.z + xv.w*wq.w;
    }
  }

  // ---- LN1 (per-lane partials + 8-wave LDS exchange) ----
  {
    float s = 0.f;
    #pragma unroll
    for (int d = 0; d < 16; ++d) s += acc[d];
    part[wv][lane] = s;
  }
  __syncthreads();
  float tot = 0.f;
  #pragma unroll
  for (int w = 0; w < 8; ++w) tot += part[w][lane];
  float mean = tot * 0.0078125f;
  __syncthreads();                 // WAR on part
  {
    float s2 = 0.f;
    #pragma unroll
    for (int d = 0; d < 16; ++d){ acc[d] -= mean; s2 += acc[d] * acc[d]; }
    part[wv][lane] = s2;
  }
  __syncthreads();
  float tv = 0.f;
  #pragma unroll
  for (int w = 0; w < 8; ++w) tv += part[w][lane];
  float rs = rsqrtf(tv * 0.0078125f + 1e-5f);
  #pragma unroll
  for (int q = 0; q < 4; ++q){
    float4 hv;
    hv.x = acc[q*4+0] * rs * g1[nbase+q*4+0] + b1[nbase+q*4+0];
    hv.y = acc[q*4+1] * rs * g1[nbase+q*4+1] + b1[nbase+q*4+1];
    hv.z = acc[q*4+2] * rs * g1[nbase+q*4+2] + b1[nbase+q*4+2];
    hv.w = acc[q*4+3] * rs * g1[nbase+q*4+3] + b1[nbase+q*4+3];
    *(float4*)&hn[lane][nbase + q*4] = hv;
  }
  __syncthreads();                 // hn complete (also WAR on part)

  // ---- GEMM2: a2[d] = hn[lane] . w2[nbase+d] ----
  float a2[16];
  #pragma unroll
  for (int d = 0; d < 16; ++d) a2[d] = 0.f;
  #pragma unroll 2
  for (int k4 = 0; k4 < 32; ++k4){
    float4 xv = *(const float4*)&hn[lane][k4 * 4];
    #pragma unroll
    for (int d = 0; d < 16; ++d){
      float4 wq = ((const float4*)(w2 + (size_t)(nbase + d) * 128))[k4];
      a2[d] += xv.x*wq.x + xv.y*wq.y + xv.z*wq.z + xv.w*wq.w;
    }
  }

  // ---- LN2 + ReLU + bf16 pack ----
  {
    float s = 0.f;
    #pragma unroll
    for (int d = 0; d < 16; ++d) s += a2[d];
    part[wv][lane] = s;
  }
  __syncthreads();
  float tot2 = 0.f;
  #pragma unroll
  for (int w = 0; w < 8; ++w) tot2 += part[w][lane];
  float mean2 = tot2 * 0.0078125f;
  __syncthreads();
  {
    float s2 = 0.f;
    #pragma unroll
    for (int d = 0; d < 16; ++d){ a2[d] -= mean2; s2 += a2[d] * a2[d]; }
    part[wv][lane] = s2;
  }
  __syncthreads();
  float tv2 = 0.f;
  #pragma unroll
  for (int w = 0; w < 8; ++w) tv2 += part[w][lane];
  float rs2 = rsqrtf(tv2 * 0.0078125f + 1e-5f);

  uint* orow = fBw + (size_t)(rg0 + lane) * 64 + (nbase >> 1);
  #pragma unroll
  for (int p = 0; p < 8; ++p){
    float o0 = fmaxf(a2[2*p]   * rs2 * g2[nbase+2*p]   + b2[nbase+2*p],   0.f);
    float o1 = fmaxf(a2[2*p+1] * rs2 * g2[nbase+2*p+1] + b2[nbase+2*p+1], 0.f);
    orow[p] = (uint)f2b(o0) | ((uint)f2b(o1) << 16);
  }
}

// ---------------- K2: fused KNN top-16 + gather/max-pool (unchanged from R8) ----------------
__device__ __forceinline__ u64 shfl64(u64 v, int src){
  int lo = __shfl((int)(uint)v, src, 64);
  int hi = __shfl((int)(uint)(v >> 32), src, 64);
  return ((u64)(uint)hi << 32) | (uint)lo;
}

__device__ __forceinline__ u64 bsort64(u64 key, int lane){
  #pragma unroll
  for (int k = 2; k <= 64; k <<= 1){
    #pragma unroll
    for (int j = k >> 1; j > 0; j >>= 1){
      u64 o = shfl64(key, lane ^ j);
      bool lower = (lane & j) == 0;
      bool down  = (lane & k) == 0;
      bool takeMin = (lower == down);
      bool oLess = o < key;
      key = (oLess == takeMin) ? o : key;
    }
  }
  return key;
}
__device__ __forceinline__ u64 bmerge64(u64 key, int lane){
  #pragma unroll
  for (int j = 32; j > 0; j >>= 1){
    u64 o = shfl64(key, lane ^ j);
    bool lower = (lane & j) == 0;
    bool oLess = o < key;
    key = (oLess == lower) ? o : key;
  }
  return key;
}

__device__ __forceinline__ u64 drain(u64* ldsq, int& qcount, float& hf, int lane){
  u64 a = (lane < qcount) ? ldsq[lane] : ~0ull;
  a = bsort64(a, lane);
  if (qcount > 64){
    u64 b = (64 + lane < qcount) ? ldsq[64 + lane] : ~0ull;
    b = bsort64(b, lane);
    u64 br = shfl64(b, 63 - lane);
    a = a < br ? a : br;
    a = bmerge64(a, lane);
  }
  if (lane < 16) ldsq[lane] = a;
  u64 h = shfl64(a, 15);
  hf = unford((uint)(h >> 32));
  qcount = 16;
  return a;
}

__global__ __launch_bounds__(256) void knn_pool_k(const float4* __restrict__ cF,
                                                  const int* __restrict__ keep,
                                                  const uint* __restrict__ fB32,
                                                  float* __restrict__ out1){
  __shared__ u64 q8[4][128];
  int tid = threadIdx.x, lane = tid & 63;
  int wv = tid >> 6;
  int g = blockIdx.x * 4 + wv;
  int n = g >> 11, i = g & 2047;
  u64* ldsq = q8[wv];
  int kidx = keep[i];
  float4 qf = cF[(n << 13) + kidx];
  const float4* base = cF + (n << 13);

  float hf  = 3.4e38f;
  float hfr = 3.4e38f;
  int qcount = 0;

  #define PROC(cf, jidx) { \
    float dotf = __builtin_fmaf(qf.x,(cf).x, __builtin_fmaf(qf.y,(cf).y, qf.z*(cf).z)); \
    float d2f  = __builtin_fmaf(-2.0f, dotf, qf.w + (cf).w); \
    bool pred = d2f <= hfr; \
    u64 bal = __ballot(pred); \
    if (bal){ \
      if (pred){ \
        float d2; \
        { \
          _Pragma("clang fp contract(off)") \
          float dot = qf.x*(cf).x + qf.y*(cf).y + qf.z*(cf).z; \
          d2 = (qf.w + (cf).w) - 2.0f * dot; \
        } \
        u64 key = ((u64)ford(d2) << 32) | (uint)(jidx); \
        int rel = __builtin_amdgcn_mbcnt_lo((uint)bal, 0); \
        rel = __builtin_amdgcn_mbcnt_hi((uint)(bal >> 32), rel); \
        ldsq[qcount + rel] = key; \
      } \
      qcount += __popcll(bal); \
      if (qcount >= 49){ drain(ldsq, qcount, hf, lane); hfr = hf + 1e-3f; } \
    } \
  }

  for (int b = 0; b < 128; b += 4){
    const float4* p = base + (b << 6) + lane;
    float4 c0 = p[0];
    float4 c1 = p[64];
    float4 c2 = p[128];
    float4 c3 = p[192];
    int j0 = (b << 6) + lane;
    PROC(c0, j0);
    PROC(c1, j0 + 64);
    PROC(c2, j0 + 128);
    PROC(c3, j0 + 192);
  }
  u64 a = drain(ldsq, qcount, hf, lane);
  #undef PROC

  const uint* frow = fB32 + ((size_t)(n << 11) << 6);
  float m0 = -3.4e38f, m1 = -3.4e38f;
  #pragma unroll
  for (int k = 0; k < 16; ++k){
    int idx = (int)(shfl64(a, k) & 2047u);
    uint u = frow[((size_t)idx << 6) + lane];
    float f0 = __uint_as_float((u & 0xFFFFu) << 16);
    float f1 = __uint_as_float((u >> 16) << 16);
    m0 = fmaxf(m0, f0); m1 = fmaxf(m1, f1);
  }
  float2* o2 = (float2*)(out1 + (size_t)(i * 8 + n) * 128);
  o2[lane] = make_float2(m0, m1);
}

extern "C" void kernel_launch(void* const* d_in, const int* in_sizes, int n_in,
                              void* d_out, int out_size, void* d_ws, size_t ws_size,
                              hipStream_t stream){
  const float* coords = (const float*)d_in[0];
  const float* feat   = (const float*)d_in[1];
  const float* w1     = (const float*)d_in[2];
  const float* g1     = (const float*)d_in[3];
  const float* b1     = (const float*)d_in[4];
  const float* w2     = (const float*)d_in[5];
  const float* g2     = (const float*)d_in[6];
  const float* b2     = (const float*)d_in[7];
  const int*   keep   = (const int*)d_in[8];
  float* out0 = (float*)d_out;                    // keep_coords [2048,8,3]
  float* out1 = out0 + 49152;                     // pool_features [2048,8,128]

  char* ws = (char*)d_ws;
  float4* cF = (float4*)ws;                       // [N][L] f32x4 : 1 MB
  ushort* fB = (ushort*)(ws + (1 << 20));         // [N][L2][128] bf16 : 4 MB

  hipLaunchKernelGGL(mlp_prep_k, dim3(480), dim3(512), 0, stream,
                     feat, w1, g1, b1, w2, g2, b2, (uint*)fB, coords, keep, cF, out0);
  hipLaunchKernelGGL(knn_pool_k, dim3(4096), dim3(256), 0, stream,
                     cF, keep, (const uint*)fB, out1);
}